// Round 6
// baseline (121.812 us; speedup 1.0000x reference)
//
#include <hip/hip_runtime.h>
#include <hip/hip_bf16.h>
#include <stdint.h>

// Problem constants (match reference setup_inputs)
#define BB   16
#define CC   64
#define LL   8192
#define OO   64
#define KK   3

typedef __attribute__((ext_vector_type(8))) short short8;     // 8 bf16 = 4 VGPRs (MFMA A/B frag)
typedef __attribute__((ext_vector_type(4))) float float4_t;   // MFMA C/D frag

__device__ __forceinline__ ushort f2bf(float f) {
    uint32_t u = __float_as_uint(f);
    return (ushort)((u + 0x7FFFu + ((u >> 16) & 1u)) >> 16);  // RNE
}
__device__ __forceinline__ uint32_t pk2(float lo, float hi) {
    float2 t; t.x = lo; t.y = hi;
    __hip_bfloat162 h = __float22bfloat162_rn(t);
    return *(uint32_t*)&h;
}

// Pre-kernel: weight [O][C][K] fp32 -> wt [O][K*64 + c] bf16 (row-major over ck=k*64+c)
__global__ void wt_prep(const float* __restrict__ w, ushort* __restrict__ wt) {
    int idx = blockIdx.x * 256 + threadIdx.x;
    if (idx < OO * CC * KK) {
        int f = idx / (CC * KK);
        int rem = idx - f * (CC * KK);
        int c = rem / KK;
        int k = rem - c * KK;
        wt[f * (KK * CC) + k * CC + c] = f2bf(w[idx]);
    }
}

// Barrier-free, LDS-free: one wave owns 16 positions x all 64 filters.
// Each lane gathers x directly from global (L1/L2/L3-backed), blends in regs,
// MFMAs vs wt fragments from L2. Waves fully independent -> no lock-step stalls.
// A = sampled (m = position), B = weight (n = filter).
__global__ __launch_bounds__(256, 3) void deform_main(
    const float* __restrict__ x, const float* __restrict__ offs,
    const ushort* __restrict__ wt, const float* __restrict__ bias,
    float* __restrict__ out) {

    const int tid   = threadIdx.x;
    const int lane  = tid & 63;
    const int wv    = tid >> 6;
    const int lr    = lane & 15;            // position-in-16 (A row), filter-in-16 (B col), C col
    const int q     = lane >> 4;            // k-quad
    const int chunk = blockIdx.x * 4 + wv;  // 0..8191 independent wave-tiles
    const int bb    = chunk >> 9;           // 512 chunks per batch
    const int pos0  = (chunk & 511) * 16;
    const int n     = pos0 + lr;            // this lane's position

    const float* xb = x + (size_t)bb * (CC * LL);

    // ---- per-lane (j0, j1, w0, w1) for all 3 taps, in registers ----
    int   j0k[KK], j1k[KK];
    float w0k[KK], w1k[KK];
    {
        const float* ob = offs + ((size_t)bb * LL + n) * KK;
        const float t0 = (float)n;
        #pragma unroll
        for (int k = 0; k < KK; k++) {
            float T = t0 + (float)k + ob[k];
            T = fmaxf(T, t0);
            T = fminf(T, t0 + 2.0f);
            int U = (int)floorf(T);          // in [0, 8192] after clip below
            if (U > LL) U = LL;
            float Uf = (float)U;
            w0k[k] = fmaxf(0.f, 1.f - fabsf(Uf - T));
            w1k[k] = fmaxf(0.f, 1.f - fabsf(Uf + 1.f - T));
            // x_pad[p] = x[p-1] for 1<=p<=L; x_pad[0]=x[1]; x_pad[L+1]=x[L-2]
            int a = U - 1;  j0k[k] = (a < 0) ? 1 : a;            // x_pad[U]
            j1k[k] = (U <= LL - 1) ? U : (LL - 2);               // x_pad[U+1]
        }
    }

    // ---- gather + blend + MFMA, no sync anywhere ----
    float4_t acc0 = {0.f, 0.f, 0.f, 0.f};
    float4_t acc1 = acc0, acc2 = acc0, acc3 = acc0;

    #pragma unroll
    for (int kk = 0; kk < 6; kk++) {
        const int k  = kk >> 1;                   // kernel tap
        const int c0 = (kk & 1) * 32 + q * 8;     // channel base of this lane's 8 elems
        const float* p0 = xb + (size_t)c0 * LL + j0k[k];
        const float* p1 = xb + (size_t)c0 * LL + j1k[k];
        float xv0[8], xv1[8];
        #pragma unroll
        for (int cc = 0; cc < 8; cc++) {
            xv0[cc] = p0[(size_t)cc * LL];
            xv1[cc] = p1[(size_t)cc * LL];
        }
        const float w0 = w0k[k], w1 = w1k[k];
        union { short8 s; uint32_t u32[4]; } af;
        #pragma unroll
        for (int j = 0; j < 4; j++) {
            float v0 = w0 * xv0[2 * j]     + w1 * xv1[2 * j];
            float v1 = w0 * xv0[2 * j + 1] + w1 * xv1[2 * j + 1];
            af.u32[j] = pk2(v0, v1);
        }
        const ushort* wrow = wt + kk * 32 + q * 8;
        short8 b0 = *(const short8*)&wrow[(0 * 16 + lr) * (KK * CC)];
        short8 b1 = *(const short8*)&wrow[(1 * 16 + lr) * (KK * CC)];
        short8 b2 = *(const short8*)&wrow[(2 * 16 + lr) * (KK * CC)];
        short8 b3 = *(const short8*)&wrow[(3 * 16 + lr) * (KK * CC)];
        acc0 = __builtin_amdgcn_mfma_f32_16x16x32_bf16(af.s, b0, acc0, 0, 0, 0);
        acc1 = __builtin_amdgcn_mfma_f32_16x16x32_bf16(af.s, b1, acc1, 0, 0, 0);
        acc2 = __builtin_amdgcn_mfma_f32_16x16x32_bf16(af.s, b2, acc2, 0, 0, 0);
        acc3 = __builtin_amdgcn_mfma_f32_16x16x32_bf16(af.s, b3, acc3, 0, 0, 0);
    }

    // ---- epilogue: C/D col = lr = filter-in-tile, row = q*4+r = position -> float4 stores ----
    const int posq = pos0 + q * 4;
    float4_t accs[4] = {acc0, acc1, acc2, acc3};
    #pragma unroll
    for (int ft = 0; ft < 4; ft++) {
        const int f = ft * 16 + lr;
        const float bv = bias[f];
        float4 o;
        o.x = accs[ft][0] + bv;
        o.y = accs[ft][1] + bv;
        o.z = accs[ft][2] + bv;
        o.w = accs[ft][3] + bv;
        *(float4*)(out + ((size_t)bb * OO + f) * LL + posq) = o;
    }
}

extern "C" void kernel_launch(void* const* d_in, const int* in_sizes, int n_in,
                              void* d_out, int out_size, void* d_ws, size_t ws_size,
                              hipStream_t stream) {
    const float* x    = (const float*)d_in[0];
    const float* offs = (const float*)d_in[1];
    const float* w    = (const float*)d_in[2];
    const float* bias = (const float*)d_in[3];
    float* out = (float*)d_out;
    ushort* wt = (ushort*)d_ws;   // 12288 bf16 = 24576 B scratch

    hipLaunchKernelGGL(wt_prep, dim3((OO * CC * KK + 255) / 256), dim3(256), 0, stream, w, wt);
    hipLaunchKernelGGL(deform_main, dim3(2048), dim3(256), 0, stream,
                       x, offs, wt, bias, out);
}